// Round 16
// baseline (549.468 us; speedup 1.0000x reference)
//
#include <hip/hip_runtime.h>

typedef __attribute__((ext_vector_type(8))) short bf16x8;
typedef __attribute__((ext_vector_type(8))) unsigned short u16x8;
typedef __attribute__((ext_vector_type(4))) float f32x4;
typedef __attribute__((ext_vector_type(2))) unsigned uint2v;
typedef __attribute__((ext_vector_type(4))) unsigned uint4v;

#define DEVINL __device__ __forceinline__

constexpr int TB = 2;        // batch
constexpr int TT = 4096;     // seq len
constexpr int TD = 512;      // model dim
constexpr int TH = 8;        // heads
constexpr int THD = 64;      // head dim
constexpr int TM = TB * TT;  // 8192 flattened rows

// fp32 -> bf16 round-to-nearest-even
DEVINL unsigned short f2b(float f) {
  unsigned u = __builtin_bit_cast(unsigned, f);
  u += 0x7FFFu + ((u >> 16) & 1u);
  return (unsigned short)(u >> 16);
}

// pack 2 f32 -> 2 bf16 in one dword
DEVINL unsigned cvtpk(float lo, float hi) {
  unsigned r;
  asm("v_cvt_pk_bf16_f32 %0, %1, %2" : "=v"(r) : "v"(lo), "v"(hi));
  return r;
}

// barrier that only waits LDS ops (global stores may stay in flight)
DEVINL void lgkm_barrier() {
  asm volatile("s_waitcnt lgkmcnt(0)" ::: "memory");
  __builtin_amdgcn_s_barrier();
  __builtin_amdgcn_sched_barrier(0);
}

// ---------------------------------------------------------------------------
// Fused Q/K/V projection (unchanged).
// ---------------------------------------------------------------------------
__global__ __launch_bounds__(256, 2)
void proj_qkv(const float* __restrict__ Xq, const float* __restrict__ Xk,
              const float* __restrict__ Xv, const float* __restrict__ Wq,
              const float* __restrict__ Wk, const float* __restrict__ Wv,
              unsigned short* __restrict__ qb, unsigned short* __restrict__ kb,
              unsigned short* __restrict__ vt)
{
  constexpr int K = TD, N = TD;
  __shared__ unsigned short As[128][72];
  __shared__ unsigned short Bs[128][72];

  const int z = blockIdx.z;
  const float* X = (z == 0) ? Xq : (z == 1) ? Xk : Xv;
  const float* W = (z == 0) ? Wq : (z == 1) ? Wk : Wv;
  unsigned short* Yb = (z == 0) ? qb : (z == 1) ? kb : vt;
  const bool TR = (z == 2);

  const int t    = threadIdx.x;
  const int lane = t & 63, w = t >> 6;
  const int fr = lane & 15, fq = lane >> 4;
  const int wr = (w >> 1) * 64, wc = (w & 1) * 64;
  const int bm = blockIdx.x * 128, bn = blockIdx.y * 128;
  const int srow = t >> 1;
  const int skh  = (t & 1) * 32;

  f32x4 acc[4][4];
  #pragma unroll
  for (int i = 0; i < 4; ++i)
    #pragma unroll
    for (int j = 0; j < 4; ++j)
      acc[i][j] = f32x4{0.f, 0.f, 0.f, 0.f};

  for (int k0 = 0; k0 < K; k0 += 64) {
    const float* srcA = X + (size_t)(bm + srow) * K + k0 + skh;
    const float* srcB = W + (size_t)(bn + srow) * K + k0 + skh;
    #pragma unroll
    for (int i = 0; i < 4; ++i) {
      float4 a0 = ((const float4*)srcA)[2 * i];
      float4 a1 = ((const float4*)srcA)[2 * i + 1];
      u16x8 oa = {f2b(a0.x), f2b(a0.y), f2b(a0.z), f2b(a0.w),
                  f2b(a1.x), f2b(a1.y), f2b(a1.z), f2b(a1.w)};
      *(u16x8*)&As[srow][skh + i * 8] = oa;
      float4 b0 = ((const float4*)srcB)[2 * i];
      float4 b1 = ((const float4*)srcB)[2 * i + 1];
      u16x8 ob = {f2b(b0.x), f2b(b0.y), f2b(b0.z), f2b(b0.w),
                  f2b(b1.x), f2b(b1.y), f2b(b1.z), f2b(b1.w)};
      *(u16x8*)&Bs[srow][skh + i * 8] = ob;
    }
    __syncthreads();
    #pragma unroll
    for (int kk = 0; kk < 2; ++kk) {
      bf16x8 af[4], bfv[4];
      #pragma unroll
      for (int i = 0; i < 4; ++i)
        af[i] = *(const bf16x8*)&As[wr + i * 16 + fr][kk * 32 + fq * 8];
      #pragma unroll
      for (int j = 0; j < 4; ++j)
        bfv[j] = *(const bf16x8*)&Bs[wc + j * 16 + fr][kk * 32 + fq * 8];
      if (TR) {
        #pragma unroll
        for (int i = 0; i < 4; ++i)
          #pragma unroll
          for (int j = 0; j < 4; ++j)
            acc[i][j] = __builtin_amdgcn_mfma_f32_16x16x32_bf16(bfv[i], af[j], acc[i][j], 0, 0, 0);
      } else {
        #pragma unroll
        for (int i = 0; i < 4; ++i)
          #pragma unroll
          for (int j = 0; j < 4; ++j)
            acc[i][j] = __builtin_amdgcn_mfma_f32_16x16x32_bf16(af[i], bfv[j], acc[i][j], 0, 0, 0);
      }
    }
    __syncthreads();
  }

  if (TR) {
    #pragma unroll
    for (int i = 0; i < 4; ++i)
      #pragma unroll
      for (int j = 0; j < 4; ++j)
        #pragma unroll
        for (int ii = 0; ii < 4; ++ii) {
          const int Nidx = bn + wc + i * 16 + fq * 4 + ii;
          const int Midx = bm + wr + j * 16 + fr;
          const int h = Nidx >> 6, dd = Nidx & (THD - 1);
          const int b = Midx >> 12, tt = Midx & (TT - 1);
          Yb[((size_t)(b * TH + h) * THD + dd) * TT + tt] = f2b(acc[i][j][ii]);
        }
  } else {
    #pragma unroll
    for (int i = 0; i < 4; ++i)
      #pragma unroll
      for (int j = 0; j < 4; ++j)
        #pragma unroll
        for (int ii = 0; ii < 4; ++ii) {
          const int gm = bm + wr + i * 16 + fq * 4 + ii;
          const int gn = bn + wc + j * 16 + fr;
          Yb[(size_t)gm * N + gn] = f2b(acc[i][j][ii]);
        }
  }
}

// ---------------------------------------------------------------------------
// PASS 1: lsum + unnormalized PV -> Z + l2i.  Exact r14 structure (256,4).
// ---------------------------------------------------------------------------
__global__ __launch_bounds__(256, 4)
void attn_pass1(const unsigned short* __restrict__ Qb,
                const unsigned short* __restrict__ Kb,
                const unsigned short* __restrict__ VTg,
                float* __restrict__ Z, float* __restrict__ l2iW)
{
  __shared__ unsigned short Ks[2][32][72];     // 9.0 KB
  __shared__ unsigned short VTs[2][64][40];    // 10.0 KB

  const int t    = threadIdx.x;
  const int lane = t & 63, w = t >> 6;
  const int fr = lane & 15, fq = lane >> 4;

  const int d  = blockIdx.x;                   // 0..1023
  const int bh = 2 * (d & 7) + ((d >> 3) & 1); // 2 bh per XCD
  const int q0 = (d >> 4) * 64;
  const int b  = bh >> 3, h = bh & 7;

  const size_t rowKV  = ((size_t)(b * TT)) * TD + h * THD;
  const size_t vtBase = (size_t)bh * THD * TT;

  const int trK = t >> 3, tcK = (t & 7) * 8;
  const int trV = t >> 2, tcV = (t & 3) * 8;

  auto loadK = [&](int kv0, u16x8& r) {
    r = *(const u16x8*)(Kb + rowKV + (size_t)(kv0 + trK) * TD + tcK);
  };
  auto loadVT = [&](int kv0, u16x8& r) {
    r = *(const u16x8*)(VTg + vtBase + (size_t)trV * TT + kv0 + tcV);
  };
  auto writeK  = [&](int buf, const u16x8& r) { *(u16x8*)&Ks[buf][trK][tcK]  = r; };
  auto writeVT = [&](int buf, const u16x8& r) { *(u16x8*)&VTs[buf][trV][tcV] = r; };

  const unsigned short* qsrc = Qb + ((size_t)(b * TT + q0 + w * 16 + fr)) * TD + h * THD;
  bf16x8 aq[2];
  aq[0] = *(const bf16x8*)(qsrc + fq * 8);
  aq[1] = *(const bf16x8*)(qsrc + 32 + fq * 8);

  constexpr int KVB = 32;
  constexpr int NT = TT / KVB;                 // 128
  constexpr float K2 = 0.18033688011112042f;   // (1/8) * log2(e)

  u16x8 kA, vA, kB, vB;
  {
    u16x8 k0, v0;
    loadK(0, k0); loadVT(0, v0);
    writeK(0, k0); writeVT(0, v0);
    loadK(KVB, kB); loadVT(KVB, vB);
    lgkm_barrier();
  }

  float lsum = 0.f;
  f32x4 accz[4];
  #pragma unroll
  for (int n = 0; n < 4; ++n) accz[n] = f32x4{0.f, 0.f, 0.f, 0.f};

  for (int jp = 0; jp < NT / 2; ++jp) {
    #pragma unroll
    for (int half = 0; half < 2; ++half) {
      const int j = jp * 2 + half;
      const int cur = j & 1;
      if (j + 2 < NT) {
        if (half == 0) { loadK((j + 2) * KVB, kA); loadVT((j + 2) * KVB, vA); }
        else           { loadK((j + 2) * KVB, kB); loadVT((j + 2) * KVB, vB); }
      }
      f32x4 sv[2];
      __builtin_amdgcn_s_setprio(1);
      #pragma unroll
      for (int n = 0; n < 2; ++n) {
        f32x4 s = f32x4{0.f, 0.f, 0.f, 0.f};
        #pragma unroll
        for (int kk = 0; kk < 2; ++kk) {
          bf16x8 ak = *(const bf16x8*)&Ks[cur][n * 16 + fr][kk * 32 + fq * 8];
          s = __builtin_amdgcn_mfma_f32_16x16x32_bf16(ak, aq[kk], s, 0, 0, 0);
        }
        sv[n] = s;
      }
      __builtin_amdgcn_s_setprio(0);
      float p[2][4];
      #pragma unroll
      for (int n = 0; n < 2; ++n)
        #pragma unroll
        for (int i = 0; i < 4; ++i) {
          p[n][i] = __builtin_amdgcn_exp2f(sv[n][i] * K2);
          lsum += p[n][i];
        }
      uint4v pav = {cvtpk(p[0][0], p[0][1]), cvtpk(p[0][2], p[0][3]),
                    cvtpk(p[1][0], p[1][1]), cvtpk(p[1][2], p[1][3])};
      bf16x8 ap = __builtin_bit_cast(bf16x8, pav);
      __builtin_amdgcn_s_setprio(1);
      #pragma unroll
      for (int df = 0; df < 4; ++df) {
        uint2v lo = *(const uint2v*)&VTs[cur][df * 16 + fr][fq * 4];
        uint2v hi = *(const uint2v*)&VTs[cur][df * 16 + fr][16 + fq * 4];
        uint4v bvv = {lo[0], lo[1], hi[0], hi[1]};
        accz[df] = __builtin_amdgcn_mfma_f32_16x16x32_bf16(
            ap, __builtin_bit_cast(bf16x8, bvv), accz[df], 0, 0, 0);
      }
      __builtin_amdgcn_s_setprio(0);
      if (j + 1 < NT) {
        if (half == 0) { writeK(cur ^ 1, kB); writeVT(cur ^ 1, vB); }
        else           { writeK(cur ^ 1, kA); writeVT(cur ^ 1, vA); }
      }
      lgkm_barrier();
    }
  }

  lsum += __shfl_xor(lsum, 16, 64);
  lsum += __shfl_xor(lsum, 32, 64);

  if (fq == 0)
    l2iW[(size_t)bh * TT + q0 + w * 16 + fr] = -__log2f(lsum);

  float rls[4];
  #pragma unroll
  for (int i = 0; i < 4; ++i)
    rls[i] = 1.0f / __shfl(lsum, fq * 4 + i, 64);
  const size_t zbase = ((size_t)(b * TT + q0 + w * 16 + fq * 4)) * TD + h * THD + fr;
  #pragma unroll
  for (int df = 0; df < 4; ++df)
    #pragma unroll
    for (int i = 0; i < 4; ++i)
      Z[zbase + (size_t)i * TD + df * 16] = accz[df][i] * rls[i];
}

// ---------------------------------------------------------------------------
// PASS 2 + final GEMM in one dispatch.
// Blocks 0..511: out = Z @ Wo^T + bo, one 128x64 tile each (Z is complete:
//   pass1 is a prior kernel). Dispatched first -> overlaps the store stream.
// Blocks 512..1535: LDS-FREE phase-staggered streamer. K fragments loaded
//   per-lane directly from global (L2-resident) into register double buffers
//   fA/fB (distance-1). Chain: loads -> 4 MFMA -> exp -> 2 stores. No DS ops,
//   no barriers.
// ---------------------------------------------------------------------------
__global__ __launch_bounds__(256, 4)
void pass2_gemm(const unsigned short* __restrict__ Qb,
                const unsigned short* __restrict__ Kb,
                const float* __restrict__ l2iW,
                float* __restrict__ attnO,
                const float* __restrict__ Zf,
                const float* __restrict__ Wo,
                const float* __restrict__ bo,
                float* __restrict__ outO)
{
  __shared__ __align__(16) char smem_[27648];   // gemm branch only

  const int t    = threadIdx.x;
  const int lane = t & 63, w = t >> 6;
  const int fr = lane & 15, fq = lane >> 4;
  const int d  = blockIdx.x;

  if (d < 512) {
    // ---------------- GEMM branch: out[128x64] tile at (gm0, gn0) ----------
    auto GAs = (unsigned short (*)[72])smem_;            // [128][72]
    auto GBs = (unsigned short (*)[72])(smem_ + 18432);  // [64][72]
    const int gm0 = (d >> 3) * 128, gn0 = (d & 7) * 64;
    const int wr = (w >> 1) * 64, wc = (w & 1) * 32;
    const int srow = t >> 1, skh = (t & 1) * 32;   // GAs: 2 thr/row
    const int brow = t >> 2, bkh = (t & 3) * 16;   // GBs: 4 thr/row
    f32x4 gacc[4][2];
    #pragma unroll
    for (int i = 0; i < 4; ++i)
      #pragma unroll
      for (int j = 0; j < 2; ++j)
        gacc[i][j] = f32x4{0.f, 0.f, 0.f, 0.f};
    for (int k0 = 0; k0 < TD; k0 += 64) {
      const float* srcA = Zf + (size_t)(gm0 + srow) * TD + k0 + skh;
      #pragma unroll
      for (int i = 0; i < 4; ++i) {
        float4 a0 = ((const float4*)srcA)[2 * i];
        float4 a1 = ((const float4*)srcA)[2 * i + 1];
        u16x8 oa = {f2b(a0.x), f2b(a0.y), f2b(a0.z), f2b(a0.w),
                    f2b(a1.x), f2b(a1.y), f2b(a1.z), f2b(a1.w)};
        *(u16x8*)&GAs[srow][skh + i * 8] = oa;
      }
      const float* srcB = Wo + (size_t)(gn0 + brow) * TD + k0 + bkh;
      #pragma unroll
      for (int i = 0; i < 2; ++i) {
        float4 b0 = ((const float4*)srcB)[2 * i];
        float4 b1 = ((const float4*)srcB)[2 * i + 1];
        u16x8 ob = {f2b(b0.x), f2b(b0.y), f2b(b0.z), f2b(b0.w),
                    f2b(b1.x), f2b(b1.y), f2b(b1.z), f2b(b1.w)};
        *(u16x8*)&GBs[brow][bkh + i * 8] = ob;
      }
      __syncthreads();
      #pragma unroll
      for (int kk = 0; kk < 2; ++kk) {
        bf16x8 af[4], bfv[2];
        #pragma unroll
        for (int i = 0; i < 4; ++i)
          af[i] = *(const bf16x8*)&GAs[wr + i * 16 + fr][kk * 32 + fq * 8];
        #pragma unroll
        for (int j = 0; j < 2; ++j)
          bfv[j] = *(const bf16x8*)&GBs[wc + j * 16 + fr][kk * 32 + fq * 8];
        #pragma unroll
        for (int i = 0; i < 4; ++i)
          #pragma unroll
          for (int j = 0; j < 2; ++j)
            gacc[i][j] = __builtin_amdgcn_mfma_f32_16x16x32_bf16(af[i], bfv[j], gacc[i][j], 0, 0, 0);
      }
      __syncthreads();
    }
    #pragma unroll
    for (int i = 0; i < 4; ++i)
      #pragma unroll
      for (int j = 0; j < 2; ++j)
        #pragma unroll
        for (int ii = 0; ii < 4; ++ii) {
          const int gm = gm0 + wr + i * 16 + fq * 4 + ii;
          const int gn = gn0 + wc + j * 16 + fr;
          outO[(size_t)gm * TD + gn] = gacc[i][j][ii] + bo[gn];
        }
    return;
  }

  // ---------------- Streamer branch (LDS-free) -----------------------------
  const int ds = d - 512;                        // 0..1023
  const int bh = 2 * (ds & 7) + ((ds >> 3) & 1); // 2 bh per XCD
  const int q0 = (ds >> 4) * 64;
  const int b  = bh >> 3, h = bh & 7;

  const size_t rowKV = ((size_t)(b * TT)) * TD + h * THD;

  const unsigned short* qsrc = Qb + ((size_t)(b * TT + q0 + w * 16 + fr)) * TD + h * THD;
  bf16x8 aq0 = *(const bf16x8*)(qsrc + fq * 8);
  bf16x8 aq1 = *(const bf16x8*)(qsrc + 32 + fq * 8);

  const float l2i = l2iW[(size_t)bh * TT + q0 + w * 16 + fr];

  constexpr int KVB = 32;
  constexpr int NT = TT / KVB;                  // 128
  constexpr float K2 = 0.18033688011112042f;

  const int phase = (37 * ds + 32 * w) & (NT - 1);
  auto PH = [&](int jj) { return (jj + phase) & (NT - 1); };

  // per-lane K fragment base: row fr, col fq*8 (frag m=n*2+kk at row n*16, col +kk*32)
  const unsigned short* kfb = Kb + rowKV + (size_t)fr * TD + fq * 8;
  auto LD = [&](int j, u16x8* f) {
    const unsigned short* p = kfb + (size_t)(j * KVB) * TD;
    f[0] = *(const u16x8*)(p);
    f[1] = *(const u16x8*)(p + 32);
    f[2] = *(const u16x8*)(p + (size_t)16 * TD);
    f[3] = *(const u16x8*)(p + (size_t)16 * TD + 32);
  };

  float* arow = attnO + ((size_t)bh * TT + q0 + w * 16 + fr) * TT + fq * 4;

#define P2C(JJ, F)                                                             \
  {                                                                            \
    const int j = PH(JJ);                                                      \
    f32x4 s0 = f32x4{0.f, 0.f, 0.f, 0.f}, s1 = f32x4{0.f, 0.f, 0.f, 0.f};      \
    __builtin_amdgcn_s_setprio(1);                                             \
    s0 = __builtin_amdgcn_mfma_f32_16x16x32_bf16(__builtin_bit_cast(bf16x8, F[0]), aq0, s0, 0, 0, 0); \
    s0 = __builtin_amdgcn_mfma_f32_16x16x32_bf16(__builtin_bit_cast(bf16x8, F[1]), aq1, s0, 0, 0, 0); \
    s1 = __builtin_amdgcn_mfma_f32_16x16x32_bf16(__builtin_bit_cast(bf16x8, F[2]), aq0, s1, 0, 0, 0); \
    s1 = __builtin_amdgcn_mfma_f32_16x16x32_bf16(__builtin_bit_cast(bf16x8, F[3]), aq1, s1, 0, 0, 0); \
    __builtin_amdgcn_s_setprio(0);                                             \
    f32x4 pv0 = {__builtin_amdgcn_exp2f(fmaf(s0[0], K2, l2i)),                 \
                 __builtin_amdgcn_exp2f(fmaf(s0[1], K2, l2i)),                 \
                 __builtin_amdgcn_exp2f(fmaf(s0[2], K2, l2i)),                 \
                 __builtin_amdgcn_exp2f(fmaf(s0[3], K2, l2i))};                \
    *(f32x4*)(arow + j * KVB) = pv0;                                           \
    f32x4 pv1 = {__builtin_amdgcn_exp2f(fmaf(s1[0], K2, l2i)),                 \
                 __builtin_amdgcn_exp2f(fmaf(s1[1], K2, l2i)),                 \
                 __builtin_amdgcn_exp2f(fmaf(s1[2], K2, l2i)),                 \
                 __builtin_amdgcn_exp2f(fmaf(s1[3], K2, l2i))};                \
    *(f32x4*)(arow + j * KVB + 16) = pv1;                                      \
  }

  u16x8 fA[4], fB[4];
  LD(PH(0), fA);
  for (int jj = 0; jj < NT; jj += 2) {
    if (jj + 1 < NT) LD(PH(jj + 1), fB);
    P2C(jj, fA)
    if (jj + 2 < NT) LD(PH(jj + 2), fA);
    P2C(jj + 1, fB)
  }
#undef P2C
}

// ---------------------------------------------------------------------------
extern "C" void kernel_launch(void* const* d_in, const int* in_sizes, int n_in,
                              void* d_out, int out_size, void* d_ws, size_t ws_size,
                              hipStream_t stream) {
  const float* queries = (const float*)d_in[0];
  const float* keys    = (const float*)d_in[1];
  const float* values  = (const float*)d_in[2];
  const float* Wq = (const float*)d_in[3];
  const float* Wk = (const float*)d_in[4];
  const float* Wv = (const float*)d_in[5];
  const float* Wo = (const float*)d_in[6];
  const float* bo = (const float*)d_in[7];

  float* out  = (float*)d_out;                       // [2,4096,512]
  float* attn = out + (size_t)TM * TD;               // [2,8,4096,4096]

  unsigned short* qb = (unsigned short*)d_ws;
  unsigned short* kb = qb + (size_t)TM * TD;
  unsigned short* vt = kb + (size_t)TM * TD;
  float*          zf = (float*)(vt + (size_t)TM * TD);
  float*          l2iW = zf + (size_t)TM * TD;       // [16][4096]

  proj_qkv<<<dim3(TM / 128, TD / 128, 3), 256, 0, stream>>>(
      queries, keys, values, Wq, Wk, Wv, qb, kb, vt);

  attn_pass1<<<dim3(1024), 256, 0, stream>>>(qb, kb, vt, zf, l2iW);

  pass2_gemm<<<dim3(1536), 256, 0, stream>>>(qb, kb, l2iW, attn,
                                             zf, Wo, bo, out);
}

// Round 17
// 492.624 us; speedup vs baseline: 1.1154x; 1.1154x over previous
//
#include <hip/hip_runtime.h>

typedef __attribute__((ext_vector_type(8))) short bf16x8;
typedef __attribute__((ext_vector_type(8))) unsigned short u16x8;
typedef __attribute__((ext_vector_type(4))) float f32x4;
typedef __attribute__((ext_vector_type(2))) unsigned uint2v;
typedef __attribute__((ext_vector_type(4))) unsigned uint4v;

#define DEVINL __device__ __forceinline__

constexpr int TB = 2;        // batch
constexpr int TT = 4096;     // seq len
constexpr int TD = 512;      // model dim
constexpr int TH = 8;        // heads
constexpr int THD = 64;      // head dim
constexpr int TM = TB * TT;  // 8192 flattened rows

// fp32 -> bf16 round-to-nearest-even
DEVINL unsigned short f2b(float f) {
  unsigned u = __builtin_bit_cast(unsigned, f);
  u += 0x7FFFu + ((u >> 16) & 1u);
  return (unsigned short)(u >> 16);
}

// pack 2 f32 -> 2 bf16 in one dword
DEVINL unsigned cvtpk(float lo, float hi) {
  unsigned r;
  asm("v_cvt_pk_bf16_f32 %0, %1, %2" : "=v"(r) : "v"(lo), "v"(hi));
  return r;
}

// barrier that only waits LDS ops (global stores may stay in flight)
DEVINL void lgkm_barrier() {
  asm volatile("s_waitcnt lgkmcnt(0)" ::: "memory");
  __builtin_amdgcn_s_barrier();
  __builtin_amdgcn_sched_barrier(0);
}

// ---------------------------------------------------------------------------
// Fused Q/K/V projection (unchanged).
// ---------------------------------------------------------------------------
__global__ __launch_bounds__(256, 2)
void proj_qkv(const float* __restrict__ Xq, const float* __restrict__ Xk,
              const float* __restrict__ Xv, const float* __restrict__ Wq,
              const float* __restrict__ Wk, const float* __restrict__ Wv,
              unsigned short* __restrict__ qb, unsigned short* __restrict__ kb,
              unsigned short* __restrict__ vt)
{
  constexpr int K = TD, N = TD;
  __shared__ unsigned short As[128][72];
  __shared__ unsigned short Bs[128][72];

  const int z = blockIdx.z;
  const float* X = (z == 0) ? Xq : (z == 1) ? Xk : Xv;
  const float* W = (z == 0) ? Wq : (z == 1) ? Wk : Wv;
  unsigned short* Yb = (z == 0) ? qb : (z == 1) ? kb : vt;
  const bool TR = (z == 2);

  const int t    = threadIdx.x;
  const int lane = t & 63, w = t >> 6;
  const int fr = lane & 15, fq = lane >> 4;
  const int wr = (w >> 1) * 64, wc = (w & 1) * 64;
  const int bm = blockIdx.x * 128, bn = blockIdx.y * 128;
  const int srow = t >> 1;
  const int skh  = (t & 1) * 32;

  f32x4 acc[4][4];
  #pragma unroll
  for (int i = 0; i < 4; ++i)
    #pragma unroll
    for (int j = 0; j < 4; ++j)
      acc[i][j] = f32x4{0.f, 0.f, 0.f, 0.f};

  for (int k0 = 0; k0 < K; k0 += 64) {
    const float* srcA = X + (size_t)(bm + srow) * K + k0 + skh;
    const float* srcB = W + (size_t)(bn + srow) * K + k0 + skh;
    #pragma unroll
    for (int i = 0; i < 4; ++i) {
      float4 a0 = ((const float4*)srcA)[2 * i];
      float4 a1 = ((const float4*)srcA)[2 * i + 1];
      u16x8 oa = {f2b(a0.x), f2b(a0.y), f2b(a0.z), f2b(a0.w),
                  f2b(a1.x), f2b(a1.y), f2b(a1.z), f2b(a1.w)};
      *(u16x8*)&As[srow][skh + i * 8] = oa;
      float4 b0 = ((const float4*)srcB)[2 * i];
      float4 b1 = ((const float4*)srcB)[2 * i + 1];
      u16x8 ob = {f2b(b0.x), f2b(b0.y), f2b(b0.z), f2b(b0.w),
                  f2b(b1.x), f2b(b1.y), f2b(b1.z), f2b(b1.w)};
      *(u16x8*)&Bs[srow][skh + i * 8] = ob;
    }
    __syncthreads();
    #pragma unroll
    for (int kk = 0; kk < 2; ++kk) {
      bf16x8 af[4], bfv[4];
      #pragma unroll
      for (int i = 0; i < 4; ++i)
        af[i] = *(const bf16x8*)&As[wr + i * 16 + fr][kk * 32 + fq * 8];
      #pragma unroll
      for (int j = 0; j < 4; ++j)
        bfv[j] = *(const bf16x8*)&Bs[wc + j * 16 + fr][kk * 32 + fq * 8];
      if (TR) {
        #pragma unroll
        for (int i = 0; i < 4; ++i)
          #pragma unroll
          for (int j = 0; j < 4; ++j)
            acc[i][j] = __builtin_amdgcn_mfma_f32_16x16x32_bf16(bfv[i], af[j], acc[i][j], 0, 0, 0);
      } else {
        #pragma unroll
        for (int i = 0; i < 4; ++i)
          #pragma unroll
          for (int j = 0; j < 4; ++j)
            acc[i][j] = __builtin_amdgcn_mfma_f32_16x16x32_bf16(af[i], bfv[j], acc[i][j], 0, 0, 0);
      }
    }
    __syncthreads();
  }

  if (TR) {
    #pragma unroll
    for (int i = 0; i < 4; ++i)
      #pragma unroll
      for (int j = 0; j < 4; ++j)
        #pragma unroll
        for (int ii = 0; ii < 4; ++ii) {
          const int Nidx = bn + wc + i * 16 + fq * 4 + ii;
          const int Midx = bm + wr + j * 16 + fr;
          const int h = Nidx >> 6, dd = Nidx & (THD - 1);
          const int b = Midx >> 12, tt = Midx & (TT - 1);
          Yb[((size_t)(b * TH + h) * THD + dd) * TT + tt] = f2b(acc[i][j][ii]);
        }
  } else {
    #pragma unroll
    for (int i = 0; i < 4; ++i)
      #pragma unroll
      for (int j = 0; j < 4; ++j)
        #pragma unroll
        for (int ii = 0; ii < 4; ++ii) {
          const int gm = bm + wr + i * 16 + fq * 4 + ii;
          const int gn = bn + wc + j * 16 + fr;
          Yb[(size_t)gm * N + gn] = f2b(acc[i][j][ii]);
        }
  }
}

// ---------------------------------------------------------------------------
// PASS 1: lsum + unnormalized PV -> Z + l2i.  Exact r14 structure (256,4).
// ---------------------------------------------------------------------------
__global__ __launch_bounds__(256, 4)
void attn_pass1(const unsigned short* __restrict__ Qb,
                const unsigned short* __restrict__ Kb,
                const unsigned short* __restrict__ VTg,
                float* __restrict__ Z, float* __restrict__ l2iW)
{
  __shared__ unsigned short Ks[2][32][72];     // 9.0 KB
  __shared__ unsigned short VTs[2][64][40];    // 10.0 KB

  const int t    = threadIdx.x;
  const int lane = t & 63, w = t >> 6;
  const int fr = lane & 15, fq = lane >> 4;

  const int d  = blockIdx.x;                   // 0..1023
  const int bh = 2 * (d & 7) + ((d >> 3) & 1); // 2 bh per XCD
  const int q0 = (d >> 4) * 64;
  const int b  = bh >> 3, h = bh & 7;

  const size_t rowKV  = ((size_t)(b * TT)) * TD + h * THD;
  const size_t vtBase = (size_t)bh * THD * TT;

  const int trK = t >> 3, tcK = (t & 7) * 8;
  const int trV = t >> 2, tcV = (t & 3) * 8;

  auto loadK = [&](int kv0, u16x8& r) {
    r = *(const u16x8*)(Kb + rowKV + (size_t)(kv0 + trK) * TD + tcK);
  };
  auto loadVT = [&](int kv0, u16x8& r) {
    r = *(const u16x8*)(VTg + vtBase + (size_t)trV * TT + kv0 + tcV);
  };
  auto writeK  = [&](int buf, const u16x8& r) { *(u16x8*)&Ks[buf][trK][tcK]  = r; };
  auto writeVT = [&](int buf, const u16x8& r) { *(u16x8*)&VTs[buf][trV][tcV] = r; };

  const unsigned short* qsrc = Qb + ((size_t)(b * TT + q0 + w * 16 + fr)) * TD + h * THD;
  bf16x8 aq[2];
  aq[0] = *(const bf16x8*)(qsrc + fq * 8);
  aq[1] = *(const bf16x8*)(qsrc + 32 + fq * 8);

  constexpr int KVB = 32;
  constexpr int NT = TT / KVB;                 // 128
  constexpr float K2 = 0.18033688011112042f;   // (1/8) * log2(e)

  u16x8 kA, vA, kB, vB;
  {
    u16x8 k0, v0;
    loadK(0, k0); loadVT(0, v0);
    writeK(0, k0); writeVT(0, v0);
    loadK(KVB, kB); loadVT(KVB, vB);
    lgkm_barrier();
  }

  float lsum = 0.f;
  f32x4 accz[4];
  #pragma unroll
  for (int n = 0; n < 4; ++n) accz[n] = f32x4{0.f, 0.f, 0.f, 0.f};

  for (int jp = 0; jp < NT / 2; ++jp) {
    #pragma unroll
    for (int half = 0; half < 2; ++half) {
      const int j = jp * 2 + half;
      const int cur = j & 1;
      if (j + 2 < NT) {
        if (half == 0) { loadK((j + 2) * KVB, kA); loadVT((j + 2) * KVB, vA); }
        else           { loadK((j + 2) * KVB, kB); loadVT((j + 2) * KVB, vB); }
      }
      f32x4 sv[2];
      __builtin_amdgcn_s_setprio(1);
      #pragma unroll
      for (int n = 0; n < 2; ++n) {
        f32x4 s = f32x4{0.f, 0.f, 0.f, 0.f};
        #pragma unroll
        for (int kk = 0; kk < 2; ++kk) {
          bf16x8 ak = *(const bf16x8*)&Ks[cur][n * 16 + fr][kk * 32 + fq * 8];
          s = __builtin_amdgcn_mfma_f32_16x16x32_bf16(ak, aq[kk], s, 0, 0, 0);
        }
        sv[n] = s;
      }
      __builtin_amdgcn_s_setprio(0);
      float p[2][4];
      #pragma unroll
      for (int n = 0; n < 2; ++n)
        #pragma unroll
        for (int i = 0; i < 4; ++i) {
          p[n][i] = __builtin_amdgcn_exp2f(sv[n][i] * K2);
          lsum += p[n][i];
        }
      uint4v pav = {cvtpk(p[0][0], p[0][1]), cvtpk(p[0][2], p[0][3]),
                    cvtpk(p[1][0], p[1][1]), cvtpk(p[1][2], p[1][3])};
      bf16x8 ap = __builtin_bit_cast(bf16x8, pav);
      __builtin_amdgcn_s_setprio(1);
      #pragma unroll
      for (int df = 0; df < 4; ++df) {
        uint2v lo = *(const uint2v*)&VTs[cur][df * 16 + fr][fq * 4];
        uint2v hi = *(const uint2v*)&VTs[cur][df * 16 + fr][16 + fq * 4];
        uint4v bvv = {lo[0], lo[1], hi[0], hi[1]};
        accz[df] = __builtin_amdgcn_mfma_f32_16x16x32_bf16(
            ap, __builtin_bit_cast(bf16x8, bvv), accz[df], 0, 0, 0);
      }
      __builtin_amdgcn_s_setprio(0);
      if (j + 1 < NT) {
        if (half == 0) { writeK(cur ^ 1, kB); writeVT(cur ^ 1, vB); }
        else           { writeK(cur ^ 1, kA); writeVT(cur ^ 1, vA); }
      }
      lgkm_barrier();
    }
  }

  lsum += __shfl_xor(lsum, 16, 64);
  lsum += __shfl_xor(lsum, 32, 64);

  if (fq == 0)
    l2iW[(size_t)bh * TT + q0 + w * 16 + fr] = -__log2f(lsum);

  float rls[4];
  #pragma unroll
  for (int i = 0; i < 4; ++i)
    rls[i] = 1.0f / __shfl(lsum, fq * 4 + i, 64);
  const size_t zbase = ((size_t)(b * TT + q0 + w * 16 + fq * 4)) * TD + h * THD + fr;
  #pragma unroll
  for (int df = 0; df < 4; ++df)
    #pragma unroll
    for (int i = 0; i < 4; ++i)
      Z[zbase + (size_t)i * TD + df * 16] = accz[df][i] * rls[i];
}

// ---------------------------------------------------------------------------
// PASS 2 + final GEMM in one dispatch (single delta vs r14).
// Blocks 0..511: out = Z @ Wo^T + bo, one 128x64 tile each. Z is complete
//   (pass1 is a prior kernel) -> no gate needed. Dispatched first so they
//   overlap under the store stream.
// Blocks 512..1535: r14's pass-2 streamer VERBATIM (per-wave double-buffered
//   LDS staging KsW[4][2][32][72], named sA/sB distance-2 sets, phase
//   stagger, barrier-free).
// LDS union 36.9 KB -> 4 blocks/CU at launch_bounds(256,4).
// ---------------------------------------------------------------------------
__global__ __launch_bounds__(256, 4)
void pass2_gemm(const unsigned short* __restrict__ Qb,
                const unsigned short* __restrict__ Kb,
                const float* __restrict__ l2iW,
                float* __restrict__ attnO,
                const float* __restrict__ Zf,
                const float* __restrict__ Wo,
                const float* __restrict__ bo,
                float* __restrict__ outO)
{
  __shared__ __align__(16) char smem_[36864];

  const int t    = threadIdx.x;
  const int lane = t & 63, w = t >> 6;
  const int fr = lane & 15, fq = lane >> 4;
  const int d  = blockIdx.x;

  if (d < 512) {
    // ---------------- GEMM branch: out[128x64] tile at (gm0, gn0) ----------
    auto GAs = (unsigned short (*)[72])smem_;            // [128][72]
    auto GBs = (unsigned short (*)[72])(smem_ + 18432);  // [64][72]
    const int gm0 = (d >> 3) * 128, gn0 = (d & 7) * 64;
    const int wr = (w >> 1) * 64, wc = (w & 1) * 32;
    const int srow = t >> 1, skh = (t & 1) * 32;   // GAs: 2 thr/row
    const int brow = t >> 2, bkh = (t & 3) * 16;   // GBs: 4 thr/row
    f32x4 gacc[4][2];
    #pragma unroll
    for (int i = 0; i < 4; ++i)
      #pragma unroll
      for (int j = 0; j < 2; ++j)
        gacc[i][j] = f32x4{0.f, 0.f, 0.f, 0.f};
    for (int k0 = 0; k0 < TD; k0 += 64) {
      const float* srcA = Zf + (size_t)(gm0 + srow) * TD + k0 + skh;
      #pragma unroll
      for (int i = 0; i < 4; ++i) {
        float4 a0 = ((const float4*)srcA)[2 * i];
        float4 a1 = ((const float4*)srcA)[2 * i + 1];
        u16x8 oa = {f2b(a0.x), f2b(a0.y), f2b(a0.z), f2b(a0.w),
                    f2b(a1.x), f2b(a1.y), f2b(a1.z), f2b(a1.w)};
        *(u16x8*)&GAs[srow][skh + i * 8] = oa;
      }
      const float* srcB = Wo + (size_t)(gn0 + brow) * TD + k0 + bkh;
      #pragma unroll
      for (int i = 0; i < 2; ++i) {
        float4 b0 = ((const float4*)srcB)[2 * i];
        float4 b1 = ((const float4*)srcB)[2 * i + 1];
        u16x8 ob = {f2b(b0.x), f2b(b0.y), f2b(b0.z), f2b(b0.w),
                    f2b(b1.x), f2b(b1.y), f2b(b1.z), f2b(b1.w)};
        *(u16x8*)&GBs[brow][bkh + i * 8] = ob;
      }
      __syncthreads();
      #pragma unroll
      for (int kk = 0; kk < 2; ++kk) {
        bf16x8 af[4], bfv[2];
        #pragma unroll
        for (int i = 0; i < 4; ++i)
          af[i] = *(const bf16x8*)&GAs[wr + i * 16 + fr][kk * 32 + fq * 8];
        #pragma unroll
        for (int j = 0; j < 2; ++j)
          bfv[j] = *(const bf16x8*)&GBs[wc + j * 16 + fr][kk * 32 + fq * 8];
        #pragma unroll
        for (int i = 0; i < 4; ++i)
          #pragma unroll
          for (int j = 0; j < 2; ++j)
            gacc[i][j] = __builtin_amdgcn_mfma_f32_16x16x32_bf16(af[i], bfv[j], gacc[i][j], 0, 0, 0);
      }
      __syncthreads();
    }
    #pragma unroll
    for (int i = 0; i < 4; ++i)
      #pragma unroll
      for (int j = 0; j < 2; ++j)
        #pragma unroll
        for (int ii = 0; ii < 4; ++ii) {
          const int gm = gm0 + wr + i * 16 + fq * 4 + ii;
          const int gn = gn0 + wc + j * 16 + fr;
          outO[(size_t)gm * TD + gn] = gacc[i][j][ii] + bo[gn];
        }
    return;
  }

  // ---------------- Streamer branch: r14 pass-2 verbatim -------------------
  auto KsW = (unsigned short (*)[2][32][72])smem_;   // [4][2][32][72]

  const int ds = d - 512;                        // 0..1023
  const int bh = 2 * (ds & 7) + ((ds >> 3) & 1); // 2 bh per XCD
  const int q0 = (ds >> 4) * 64;
  const int b  = bh >> 3, h = bh & 7;

  const size_t rowKV = ((size_t)(b * TT)) * TD + h * THD;

  const unsigned short* qsrc = Qb + ((size_t)(b * TT + q0 + w * 16 + fr)) * TD + h * THD;
  bf16x8 aq[2];
  aq[0] = *(const bf16x8*)(qsrc + fq * 8);
  aq[1] = *(const bf16x8*)(qsrc + 32 + fq * 8);

  const float l2i = l2iW[(size_t)bh * TT + q0 + w * 16 + fr];

  constexpr int KVB = 32;
  constexpr int NT = TT / KVB;                  // 128
  constexpr float K2 = 0.18033688011112042f;

  const int phase = (37 * ds + 32 * w) & (NT - 1);
  const int prow = lane >> 3, pcol = (lane & 7) * 8;

  u16x8 sA[4], sB[4];
  auto loadKW = [&](int kvt, u16x8* s) {
    #pragma unroll
    for (int i = 0; i < 4; ++i)
      s[i] = *(const u16x8*)(Kb + rowKV +
               (size_t)(kvt * KVB + i * 8 + prow) * TD + pcol);
  };
  auto writeKW = [&](int buf, const u16x8* s) {
    #pragma unroll
    for (int i = 0; i < 4; ++i)
      *(u16x8*)&KsW[w][buf][i * 8 + prow][pcol] = s[i];
  };
  auto PH = [&](int jj) { return (jj + phase) & (NT - 1); };

  float* arow = attnO + ((size_t)bh * TT + q0 + w * 16 + fr) * TT + fq * 4;

#define P2_COMPUTE(JJ, BUF)                                                    \
  {                                                                            \
    const int j = PH(JJ);                                                      \
    f32x4 sv[2];                                                               \
    __builtin_amdgcn_s_setprio(1);                                             \
    _Pragma("unroll")                                                          \
    for (int n = 0; n < 2; ++n) {                                              \
      f32x4 s = f32x4{0.f, 0.f, 0.f, 0.f};                                     \
      _Pragma("unroll")                                                        \
      for (int kk = 0; kk < 2; ++kk) {                                         \
        bf16x8 ak = *(const bf16x8*)&KsW[w][(BUF)][n * 16 + fr][kk * 32 + fq * 8]; \
        s = __builtin_amdgcn_mfma_f32_16x16x32_bf16(ak, aq[kk], s, 0, 0, 0);   \
      }                                                                        \
      sv[n] = s;                                                               \
    }                                                                          \
    __builtin_amdgcn_s_setprio(0);                                             \
    _Pragma("unroll")                                                          \
    for (int n = 0; n < 2; ++n) {                                              \
      f32x4 pv4 = {__builtin_amdgcn_exp2f(fmaf(sv[n][0], K2, l2i)),            \
                   __builtin_amdgcn_exp2f(fmaf(sv[n][1], K2, l2i)),            \
                   __builtin_amdgcn_exp2f(fmaf(sv[n][2], K2, l2i)),            \
                   __builtin_amdgcn_exp2f(fmaf(sv[n][3], K2, l2i))};           \
      *(f32x4*)(arow + j * KVB + n * 16) = pv4;                                \
    }                                                                          \
  }

  // prologue: tile0 -> buf0; tile1 -> sB
  loadKW(PH(0), sA);
  writeKW(0, sA);              // compiler inserts the one prologue vmcnt
  loadKW(PH(1), sB);

  for (int jp = 0; jp < NT / 2; ++jp) {
    const int jj0 = 2 * jp;
    if (jj0 + 2 < NT) loadKW(PH(jj0 + 2), sA);
    P2_COMPUTE(jj0, 0)
    writeKW(1, sB);
    if (jj0 + 3 < NT) loadKW(PH(jj0 + 3), sB);
    P2_COMPUTE(jj0 + 1, 1)
    if (jj0 + 2 < NT) writeKW(0, sA);
  }
#undef P2_COMPUTE
}

// ---------------------------------------------------------------------------
extern "C" void kernel_launch(void* const* d_in, const int* in_sizes, int n_in,
                              void* d_out, int out_size, void* d_ws, size_t ws_size,
                              hipStream_t stream) {
  const float* queries = (const float*)d_in[0];
  const float* keys    = (const float*)d_in[1];
  const float* values  = (const float*)d_in[2];
  const float* Wq = (const float*)d_in[3];
  const float* Wk = (const float*)d_in[4];
  const float* Wv = (const float*)d_in[5];
  const float* Wo = (const float*)d_in[6];
  const float* bo = (const float*)d_in[7];

  float* out  = (float*)d_out;                       // [2,4096,512]
  float* attn = out + (size_t)TM * TD;               // [2,8,4096,4096]

  unsigned short* qb = (unsigned short*)d_ws;
  unsigned short* kb = qb + (size_t)TM * TD;
  unsigned short* vt = kb + (size_t)TM * TD;
  float*          zf = (float*)(vt + (size_t)TM * TD);
  float*          l2iW = zf + (size_t)TM * TD;       // [16][4096]

  proj_qkv<<<dim3(TM / 128, TD / 128, 3), 256, 0, stream>>>(
      queries, keys, values, Wq, Wk, Wv, qb, kb, vt);

  attn_pass1<<<dim3(1024), 256, 0, stream>>>(qb, kb, vt, zf, l2iW);

  pass2_gemm<<<dim3(1536), 256, 0, stream>>>(qb, kb, l2iW, attn,
                                             zf, Wo, bo, out);
}